// Round 1
// 1848.786 us; speedup vs baseline: 1.1307x; 1.1307x over previous
//
#include <hip/hip_runtime.h>
#include <math.h>

typedef unsigned short ushort_t;
using short8 = __attribute__((ext_vector_type(8))) short;
using f32x4  = __attribute__((ext_vector_type(4))) float;

#define N_TOK 2048
#define DIM   1024
#define D3    3072
#define NHEAD 16
#define DH    64
#define TT    512
#define HID   4096
#define NEXP  8

__device__ __forceinline__ float bf2f(ushort_t u){
  union { unsigned int i; float f; } x; x.i = ((unsigned int)u) << 16; return x.f;
}
__device__ __forceinline__ ushort_t f2bf(float f){
  union { unsigned int i; float f; } x; x.f = f;
  unsigned int r = x.i + 0x7fffu + ((x.i >> 16) & 1u);
  return (ushort_t)(r >> 16);
}
__device__ __forceinline__ float gelu_f(float x){
  const float c = 0.7978845608028654f; // sqrt(2/pi)
  float t = tanhf(c * (x + 0.044715f * x * x * x));
  return 0.5f * x * (1.0f + t);
}

// ------- LayerNorm ---------------------------------------------------------
// MODE 1: write f32 out + bf16 outhi            (ln2: gate needs f32, MoE bf16)
// MODE 2: write bf16 hi + bf16 lo only          (ln1: feeds split-bf16 MFMA GEMM)
template<int MODE>
__global__ __launch_bounds__(256) void ln_k(const float* __restrict__ xin,
                                            const float* __restrict__ w,
                                            const float* __restrict__ b,
                                            float* __restrict__ out,
                                            ushort_t* __restrict__ outhi,
                                            ushort_t* __restrict__ outlo){
  int tok = blockIdx.x;
  int t = threadIdx.x;
  float vals[4]; float s = 0.f, ss = 0.f;
#pragma unroll
  for (int i = 0; i < 4; i++){
    int d = t + i * 256;
    float v = xin[(size_t)tok * DIM + d];
    vals[i] = v; s += v; ss += v * v;
  }
  __shared__ float rs[256], rq[256];
  rs[t] = s; rq[t] = ss; __syncthreads();
  for (int k = 128; k > 0; k >>= 1){
    if (t < k){ rs[t] += rs[t + k]; rq[t] += rq[t + k]; }
    __syncthreads();
  }
  float mu  = rs[0] * (1.0f / DIM);
  float var = rq[0] * (1.0f / DIM) - mu * mu;
  float inv = rsqrtf(var + 1e-5f);
#pragma unroll
  for (int i = 0; i < 4; i++){
    int d = t + i * 256;
    float r = (vals[i] - mu) * inv * w[d] + b[d];
    size_t idx = (size_t)tok * DIM + d;
    if (MODE == 1){
      out[idx] = r;
      outhi[idx] = f2bf(r);
    } else {
      ushort_t hv = f2bf(r);
      outhi[idx] = hv;
      outlo[idx] = f2bf(r - bf2f(hv));
    }
  }
}

// -------- Transpose-convert split: src f32 [R][C] -> hi/lo bf16 [C][R] ----
__global__ __launch_bounds__(256) void convT2(const float* __restrict__ src,
                                              ushort_t* __restrict__ dhi,
                                              ushort_t* __restrict__ dlo,
                                              int R, int C){
  __shared__ float tile[64][65];
  int r0 = blockIdx.y * 64, c0 = blockIdx.x * 64;
  int t = threadIdx.x;
  int tc = t & 15, tr = t >> 4;
#pragma unroll
  for (int i = 0; i < 4; i++){
    int r = tr + i * 16;
    float4 v = *(const float4*)&src[(size_t)(r0 + r) * C + c0 + tc * 4];
    tile[r][tc*4 + 0] = v.x; tile[r][tc*4 + 1] = v.y;
    tile[r][tc*4 + 2] = v.z; tile[r][tc*4 + 3] = v.w;
  }
  __syncthreads();
#pragma unroll
  for (int i = 0; i < 4; i++){
    int c = tr + i * 16;                     // output row = source col
    float v0 = tile[tc*4 + 0][c];
    float v1 = tile[tc*4 + 1][c];
    float v2 = tile[tc*4 + 2][c];
    float v3 = tile[tc*4 + 3][c];
    ushort4 oh, ol;
    oh.x = f2bf(v0); ol.x = f2bf(v0 - bf2f(oh.x));
    oh.y = f2bf(v1); ol.y = f2bf(v1 - bf2f(oh.y));
    oh.z = f2bf(v2); ol.z = f2bf(v2 - bf2f(oh.z));
    oh.w = f2bf(v3); ol.w = f2bf(v3 - bf2f(oh.w));
    size_t o = (size_t)(c0 + c) * R + r0 + tc * 4;
    *(ushort4*)&dhi[o] = oh;
    *(ushort4*)&dlo[o] = ol;
  }
}

// -------- Split-bf16 MFMA GEMM: C = A*B + bias (+Res), near-f32 accuracy --
// A = Ahi+Alo bf16 [M][K]; B given transposed as BThi/BTlo bf16 [N][K].
// A*B ~= Ahi*Bhi + Ahi*Blo + Alo*Bhi (lo*lo term ~2^-18, dropped).
// EPI 0: C = acc + bias.  EPI 1: C = acc + bias + Res.
#define TBM 128
#define TBN 128
#define TBK 32
#define LDK 40   // padded LDS row stride in bf16 elems

template<int EPI>
__global__ __launch_bounds__(256) void gemm_split(
    const ushort_t* __restrict__ Ahi, const ushort_t* __restrict__ Alo,
    const ushort_t* __restrict__ Bhi, const ushort_t* __restrict__ Blo,
    const float* __restrict__ bias,
    float* __restrict__ C, const float* __restrict__ Res,
    int Nn, int K)
{
  int bm = blockIdx.y * TBM, bn = blockIdx.x * TBN;
  __shared__ ushort_t Ah[TBM * LDK];
  __shared__ ushort_t Al[TBM * LDK];
  __shared__ ushort_t Bh[TBN * LDK];
  __shared__ ushort_t Bl[TBN * LDK];
  int t = threadIdx.x;
  int lane = t & 63, wave = t >> 6;
  int wm = (wave & 1) * 64, wn = (wave >> 1) * 64;

  // staging: 2 passes x 256 threads x 16B per array
  int r0 = t >> 2, r1 = r0 + 64;
  int kc = (t & 3) * 8;
  const ushort_t* ah0 = Ahi + (size_t)(bm + r0) * K + kc;
  const ushort_t* ah1 = Ahi + (size_t)(bm + r1) * K + kc;
  const ushort_t* al0 = Alo + (size_t)(bm + r0) * K + kc;
  const ushort_t* al1 = Alo + (size_t)(bm + r1) * K + kc;
  const ushort_t* bh0 = Bhi + (size_t)(bn + r0) * K + kc;
  const ushort_t* bh1 = Bhi + (size_t)(bn + r1) * K + kc;
  const ushort_t* bl0 = Blo + (size_t)(bn + r0) * K + kc;
  const ushort_t* bl1 = Blo + (size_t)(bn + r1) * K + kc;

  f32x4 acc[4][4] = {};
  int fm = lane & 15, fk = (lane >> 4) * 8;

  for (int k0 = 0; k0 < K; k0 += TBK){
    uint4 vah0 = *(const uint4*)(ah0 + k0);
    uint4 vah1 = *(const uint4*)(ah1 + k0);
    uint4 val0 = *(const uint4*)(al0 + k0);
    uint4 val1 = *(const uint4*)(al1 + k0);
    uint4 vbh0 = *(const uint4*)(bh0 + k0);
    uint4 vbh1 = *(const uint4*)(bh1 + k0);
    uint4 vbl0 = *(const uint4*)(bl0 + k0);
    uint4 vbl1 = *(const uint4*)(bl1 + k0);
    *(uint4*)&Ah[r0 * LDK + kc] = vah0;
    *(uint4*)&Ah[r1 * LDK + kc] = vah1;
    *(uint4*)&Al[r0 * LDK + kc] = val0;
    *(uint4*)&Al[r1 * LDK + kc] = val1;
    *(uint4*)&Bh[r0 * LDK + kc] = vbh0;
    *(uint4*)&Bh[r1 * LDK + kc] = vbh1;
    *(uint4*)&Bl[r0 * LDK + kc] = vbl0;
    *(uint4*)&Bl[r1 * LDK + kc] = vbl1;
    __syncthreads();
    short8 afh[4], afl[4], bfh[4], bfl[4];
#pragma unroll
    for (int mi = 0; mi < 4; mi++){
      afh[mi] = *(const short8*)&Ah[(wm + mi*16 + fm) * LDK + fk];
      afl[mi] = *(const short8*)&Al[(wm + mi*16 + fm) * LDK + fk];
    }
#pragma unroll
    for (int nj = 0; nj < 4; nj++){
      bfh[nj] = *(const short8*)&Bh[(wn + nj*16 + fm) * LDK + fk];
      bfl[nj] = *(const short8*)&Bl[(wn + nj*16 + fm) * LDK + fk];
    }
#pragma unroll
    for (int mi = 0; mi < 4; mi++)
#pragma unroll
      for (int nj = 0; nj < 4; nj++){
        acc[mi][nj] = __builtin_amdgcn_mfma_f32_16x16x32_bf16(afh[mi], bfh[nj], acc[mi][nj], 0, 0, 0);
        acc[mi][nj] = __builtin_amdgcn_mfma_f32_16x16x32_bf16(afh[mi], bfl[nj], acc[mi][nj], 0, 0, 0);
        acc[mi][nj] = __builtin_amdgcn_mfma_f32_16x16x32_bf16(afl[mi], bfh[nj], acc[mi][nj], 0, 0, 0);
      }
    __syncthreads();
  }

  // epilogue: C/D layout col=lane&15, row=(lane>>4)*4+reg  [m89-verified]
#pragma unroll
  for (int mi = 0; mi < 4; mi++){
    int rowbase = bm + wm + mi*16 + (lane >> 4) * 4;
#pragma unroll
    for (int nj = 0; nj < 4; nj++){
      int n = bn + wn + nj*16 + (lane & 15);
      f32x4 v = acc[mi][nj];
#pragma unroll
      for (int rg = 0; rg < 4; rg++){
        size_t idx = (size_t)(rowbase + rg) * Nn + n;
        float val = v[rg] + bias[n];
        if (EPI == 1) val += Res[idx];
        C[idx] = val;
      }
    }
  }
}

// ---------------- Attention scores: S[bh,q,k] = (Q·K)/8 -------------------
__global__ __launch_bounds__(256) void scores_k(const float* __restrict__ qkv,
                                                float* __restrict__ S){
  int bh = blockIdx.z; int b = bh >> 4, h = bh & 15;
  int q0 = blockIdx.y * 64, k0 = blockIdx.x * 64;
  __shared__ float Qs[64][68];
  __shared__ float Ks[64][68];
  int t = threadIdx.x;
  int r = t >> 2, dp = (t & 3) * 16;
  {
    const float* qp = qkv + (size_t)(b * TT + q0 + r) * D3 + h * DH + dp;
    const float* kp = qkv + (size_t)(b * TT + k0 + r) * D3 + DIM + h * DH + dp;
#pragma unroll
    for (int c = 0; c < 4; c++){
      float4 qv = *(const float4*)(qp + c * 4);
      float4 kv = *(const float4*)(kp + c * 4);
      Qs[dp + c*4 + 0][r] = qv.x; Qs[dp + c*4 + 1][r] = qv.y;
      Qs[dp + c*4 + 2][r] = qv.z; Qs[dp + c*4 + 3][r] = qv.w;
      Ks[dp + c*4 + 0][r] = kv.x; Ks[dp + c*4 + 1][r] = kv.y;
      Ks[dp + c*4 + 2][r] = kv.z; Ks[dp + c*4 + 3][r] = kv.w;
    }
  }
  __syncthreads();
  int tx = t & 15, ty = t >> 4;
  float acc[4][4] = {};
#pragma unroll 8
  for (int d = 0; d < 64; d++){
    float4 qv = *(const float4*)&Qs[d][ty * 4];
    float4 kv = *(const float4*)&Ks[d][tx * 4];
    float qa[4] = {qv.x,qv.y,qv.z,qv.w};
    float ka[4] = {kv.x,kv.y,kv.z,kv.w};
#pragma unroll
    for (int i = 0; i < 4; i++)
#pragma unroll
      for (int j = 0; j < 4; j++)
        acc[i][j] += qa[i] * ka[j];
  }
#pragma unroll
  for (int i = 0; i < 4; i++)
#pragma unroll
    for (int j = 0; j < 4; j++)
      S[((size_t)bh * TT + q0 + ty*4 + i) * TT + k0 + tx*4 + j] = acc[i][j] * 0.125f;
}

// ---------------- Softmax over rows of 512 --------------------------------
__global__ __launch_bounds__(256) void softmax_k(float* __restrict__ S){
  size_t row = blockIdx.x;
  float* p = S + row * TT;
  int t = threadIdx.x;
  float v0 = p[t], v1 = p[t + 256];
  __shared__ float red[256];
  red[t] = fmaxf(v0, v1); __syncthreads();
  for (int k = 128; k > 0; k >>= 1){ if (t < k) red[t] = fmaxf(red[t], red[t + k]); __syncthreads(); }
  float m = red[0]; __syncthreads();
  float e0 = expf(v0 - m), e1 = expf(v1 - m);
  red[t] = e0 + e1; __syncthreads();
  for (int k = 128; k > 0; k >>= 1){ if (t < k) red[t] += red[t + k]; __syncthreads(); }
  float inv = 1.0f / red[0];
  p[t] = e0 * inv; p[t + 256] = e1 * inv;
}

// ------- ctx = P @ V; write bf16 hi/lo [2048][1024] for split MFMA --------
__global__ __launch_bounds__(256) void ctx_k(const float* __restrict__ P,
                                             const float* __restrict__ qkv,
                                             ushort_t* __restrict__ chi,
                                             ushort_t* __restrict__ clo){
  int bh = blockIdx.y; int b = bh >> 4, h = bh & 15;
  int q0 = blockIdx.x * 64;
  __shared__ float Ps[16][68];
  __shared__ float Vs[16][68];
  int t = threadIdx.x;
  int tx = t & 15, ty = t >> 4;
  int pq = t >> 2, pk = (t & 3) * 4;
  int vk = t >> 4, vd = (t & 15) * 4;
  float acc[4][4] = {};
  for (int kk = 0; kk < TT; kk += 16){
    float4 pv = *(const float4*)&P[((size_t)bh * TT + q0 + pq) * TT + kk + pk];
    Ps[pk + 0][pq] = pv.x; Ps[pk + 1][pq] = pv.y;
    Ps[pk + 2][pq] = pv.z; Ps[pk + 3][pq] = pv.w;
    float4 vv = *(const float4*)&qkv[(size_t)(b * TT + kk + vk) * D3 + 2 * DIM + h * DH + vd];
    Vs[vk][vd + 0] = vv.x; Vs[vk][vd + 1] = vv.y;
    Vs[vk][vd + 2] = vv.z; Vs[vk][vd + 3] = vv.w;
    __syncthreads();
#pragma unroll
    for (int k = 0; k < 16; k++){
      float4 a = *(const float4*)&Ps[k][ty * 4];
      float4 bb = *(const float4*)&Vs[k][tx * 4];
      float aa[4] = {a.x,a.y,a.z,a.w};
      float bv[4] = {bb.x,bb.y,bb.z,bb.w};
#pragma unroll
      for (int i = 0; i < 4; i++)
#pragma unroll
        for (int j = 0; j < 4; j++)
          acc[i][j] += aa[i] * bv[j];
    }
    __syncthreads();
  }
#pragma unroll
  for (int i = 0; i < 4; i++)
#pragma unroll
    for (int j = 0; j < 4; j++){
      float v = acc[i][j];
      size_t idx = (size_t)(b * TT + q0 + ty*4 + i) * DIM + h * DH + tx*4 + j;
      ushort_t hv = f2bf(v);
      chi[idx] = hv;
      clo[idx] = f2bf(v - bf2f(hv));
    }
}

// -------- Gate (exact f32) + top-2 renorm weights -------------------------
__global__ __launch_bounds__(256) void gate_k(const float* __restrict__ ln2f,
                                              const float* __restrict__ wg,
                                              float* __restrict__ we){
  int tok = blockIdx.x * 4 + (threadIdx.x >> 6);
  int lane = threadIdx.x & 63;
  float acc[8] = {};
  for (int d = lane; d < DIM; d += 64){
    float x = ln2f[(size_t)tok * DIM + d];
    float4 w0 = *(const float4*)&wg[d * 8];
    float4 w1v = *(const float4*)&wg[d * 8 + 4];
    float wv[8] = {w0.x,w0.y,w0.z,w0.w,w1v.x,w1v.y,w1v.z,w1v.w};
#pragma unroll
    for (int e = 0; e < 8; e++) acc[e] += x * wv[e];
  }
#pragma unroll
  for (int off = 32; off > 0; off >>= 1){
#pragma unroll
    for (int e = 0; e < 8; e++) acc[e] += __shfl_down(acc[e], off);
  }
  if (lane == 0){
    float m = acc[0];
    for (int e = 1; e < 8; e++) m = fmaxf(m, acc[e]);
    float pr[8], s = 0.f;
    for (int e = 0; e < 8; e++){ pr[e] = expf(acc[e] - m); s += pr[e]; }
    for (int e = 0; e < 8; e++) pr[e] /= s;
    int i0 = 0;
    for (int e = 1; e < 8; e++) if (pr[e] > pr[i0]) i0 = e;
    int i1 = (i0 == 0) ? 1 : 0;
    for (int e = 0; e < 8; e++) if (e != i0 && pr[e] > pr[i1]) i1 = e;
    float sm = pr[i0] + pr[i1];
    for (int e = 0; e < 8; e++)
      we[(size_t)tok * 8 + e] = (e == i0) ? pr[i0] / sm : ((e == i1) ? pr[i1] / sm : 0.f);
  }
}

// -------- Routing: bucket tokens per expert (device-side counts) ----------
__global__ __launch_bounds__(256) void route_k(const float* __restrict__ we,
                                               int* __restrict__ cnt,
                                               int* __restrict__ gidx,
                                               float* __restrict__ gw){
  int tok = blockIdx.x * 256 + threadIdx.x;
#pragma unroll
  for (int e = 0; e < NEXP; e++){
    float w = we[(size_t)tok * NEXP + e];
    if (w > 0.f){
      int p = atomicAdd(&cnt[e], 1);
      gidx[e * N_TOK + p] = tok;
      gw[e * N_TOK + p] = w;
    }
  }
}

// -------- Transpose-convert: src f32 [R][C] -> dst bf16 [C][R] ------------
__global__ __launch_bounds__(256) void convT(const float* __restrict__ src,
                                             ushort_t* __restrict__ dst,
                                             int R, int C){
  __shared__ float tile[64][65];
  int r0 = blockIdx.y * 64, c0 = blockIdx.x * 64;
  int t = threadIdx.x;
  int tc = t & 15, tr = t >> 4;
#pragma unroll
  for (int i = 0; i < 4; i++){
    int r = tr + i * 16;
    float4 v = *(const float4*)&src[(size_t)(r0 + r) * C + c0 + tc * 4];
    tile[r][tc*4 + 0] = v.x; tile[r][tc*4 + 1] = v.y;
    tile[r][tc*4 + 2] = v.z; tile[r][tc*4 + 3] = v.w;
  }
  __syncthreads();
#pragma unroll
  for (int i = 0; i < 4; i++){
    int c = tr + i * 16;                     // output row = source col
    ushort4 o;
    o.x = f2bf(tile[tc*4 + 0][c]);
    o.y = f2bf(tile[tc*4 + 1][c]);
    o.z = f2bf(tile[tc*4 + 2][c]);
    o.w = f2bf(tile[tc*4 + 3][c]);
    *(ushort4*)&dst[(size_t)(c0 + c) * R + r0 + tc * 4] = o;
  }
}

// -------- MFMA bf16 expert GEMM (gather/scatter rows) ---------------------
// EPI 0: A rows gathered from gidx; store Obf[r][n] = bf16(gelu(v + bias[n]))
// EPI 1: A rows dense (h1e); scatter Of[gidx[r]][n] += gw[r] * (v + bias[n])
template<int EPI>
__global__ __launch_bounds__(256) void moe_gemm(
    const ushort_t* __restrict__ A,   // bf16 [*][K]
    const ushort_t* __restrict__ BT,  // bf16 [N][K]
    const float* __restrict__ bias,   // [N]
    ushort_t* __restrict__ Obf,
    float* __restrict__ Of,
    const int* __restrict__ gidx,
    const float* __restrict__ gw,
    const int* __restrict__ cnt_e,
    int Nn, int K)
{
  int c = *cnt_e;
  int bm = blockIdx.y * TBM;
  if (bm >= c) return;
  int bn = blockIdx.x * TBN;
  __shared__ ushort_t As[TBM * LDK];
  __shared__ ushort_t Bs[TBN * LDK];
  int t = threadIdx.x;
  int lane = t & 63, wave = t >> 6;
  int wm = (wave & 1) * 64, wn = (wave >> 1) * 64;

  // staging: 2 passes x 256 threads x 16B; row = idx>>2, kc = (idx&3)*8
  int r0 = t >> 2, r1 = r0 + 64;
  int kc = (t & 3) * 8;
  size_t ga0, ga1;
  if (EPI == 0){
    int g0 = bm + r0, g1 = bm + r1;
    ga0 = (size_t)((g0 < c) ? gidx[g0] : gidx[bm]);
    ga1 = (size_t)((g1 < c) ? gidx[g1] : gidx[bm]);
  } else {
    ga0 = (size_t)(bm + r0); ga1 = (size_t)(bm + r1);
  }
  const ushort_t* a0p = A + ga0 * K + kc;
  const ushort_t* a1p = A + ga1 * K + kc;
  const ushort_t* b0p = BT + (size_t)(bn + r0) * K + kc;
  const ushort_t* b1p = BT + (size_t)(bn + r1) * K + kc;

  f32x4 acc[4][4] = {};
  int fm = lane & 15, fk = (lane >> 4) * 8;

  for (int k0 = 0; k0 < K; k0 += TBK){
    uint4 av0 = *(const uint4*)(a0p + k0);
    uint4 av1 = *(const uint4*)(a1p + k0);
    uint4 bv0 = *(const uint4*)(b0p + k0);
    uint4 bv1 = *(const uint4*)(b1p + k0);
    *(uint4*)&As[r0 * LDK + kc] = av0;
    *(uint4*)&As[r1 * LDK + kc] = av1;
    *(uint4*)&Bs[r0 * LDK + kc] = bv0;
    *(uint4*)&Bs[r1 * LDK + kc] = bv1;
    __syncthreads();
    short8 af[4], bfr[4];
#pragma unroll
    for (int mi = 0; mi < 4; mi++)
      af[mi] = *(const short8*)&As[(wm + mi*16 + fm) * LDK + fk];
#pragma unroll
    for (int nj = 0; nj < 4; nj++)
      bfr[nj] = *(const short8*)&Bs[(wn + nj*16 + fm) * LDK + fk];
#pragma unroll
    for (int mi = 0; mi < 4; mi++)
#pragma unroll
      for (int nj = 0; nj < 4; nj++)
        acc[mi][nj] = __builtin_amdgcn_mfma_f32_16x16x32_bf16(af[mi], bfr[nj], acc[mi][nj], 0, 0, 0);
    __syncthreads();
  }

  // epilogue: C/D layout col=lane&15, row=(lane>>4)*4+reg  [m89-verified]
#pragma unroll
  for (int mi = 0; mi < 4; mi++){
    int rowbase = bm + wm + mi*16 + (lane >> 4) * 4;
#pragma unroll
    for (int nj = 0; nj < 4; nj++){
      int n = bn + wn + nj*16 + (lane & 15);
      f32x4 v = acc[mi][nj];
#pragma unroll
      for (int rg = 0; rg < 4; rg++){
        int r = rowbase + rg;
        if (r < c){
          float val = v[rg] + bias[n];
          if (EPI == 0){
            Obf[(size_t)r * Nn + n] = f2bf(gelu_f(val));
          } else {
            int tok = gidx[r];
            Of[(size_t)tok * Nn + n] += gw[r] * val;
          }
        }
      }
    }
  }
}

// ---------------- Final: out = h + moe_acc (f32) --------------------------
__global__ __launch_bounds__(256) void final_k(const float* __restrict__ h,
                                               const float* __restrict__ acc,
                                               float* __restrict__ out){
  size_t i = (size_t)blockIdx.x * 256 + threadIdx.x;
  out[i] = h[i] + acc[i];
}

extern "C" void kernel_launch(void* const* d_in, const int* in_sizes, int n_in,
                              void* d_out, int out_size, void* d_ws, size_t ws_size,
                              hipStream_t stream){
  const float* x     = (const float*)d_in[0];
  const float* ln1w  = (const float*)d_in[1];
  const float* ln1b  = (const float*)d_in[2];
  const float* ln2w  = (const float*)d_in[3];
  const float* ln2b  = (const float*)d_in[4];
  const float* wqkv  = (const float*)d_in[5];
  const float* bqkv  = (const float*)d_in[6];
  const float* wo    = (const float*)d_in[7];
  const float* bo    = (const float*)d_in[8];
  const float* wgate = (const float*)d_in[9];
  const float* w1    = (const float*)d_in[10];
  const float* b1    = (const float*)d_in[11];
  const float* w2    = (const float*)d_in[12];
  const float* b2    = (const float*)d_in[13];

  // Workspace map (121 MB peak):
  //  [0,8)M    ln1hi/ln1lo bf16 (4+4) -> accb f32 (after QKV GEMM)
  //  [8,32)M   qkv f32                        (dead after ctx_k)
  //  [32,40)M  ctxhi/ctxlo bf16 (4+4)         (dead after out-proj)
  //  [40,48)M  hbuf f32                       (live to end)
  //  [48,56)M  ln2f f32                       (dead after gate)
  //  [56,57)M  webuf / cnt / bucket idx+w
  //  [57,121)M sc f32 (dead after ctx_k)
  //     overlays (sequenced): wqkvThi 6M @57 | wqkvTlo 6M @63  (dead after QKV)
  //                           woThi 2M @69 | woTlo 2M @71      (dead after o-proj)
  //                           h1e 16M @57 | w1Te 8M @73 | w2Te 8M @81 | ln2bf 4M @89
  char* ws = (char*)d_ws;
  const size_t MB = 1024 * 1024;
  ushort_t* ln1hi = (ushort_t*)(ws + 0 * MB);
  ushort_t* ln1lo = (ushort_t*)(ws + 4 * MB);
  float*    accb  = (float*)(ws + 0 * MB);
  float*    qkv   = (float*)(ws + 8 * MB);
  ushort_t* ctxhi = (ushort_t*)(ws + 32 * MB);
  ushort_t* ctxlo = (ushort_t*)(ws + 36 * MB);
  float*    hbuf  = (float*)(ws + 40 * MB);
  float*    ln2f  = (float*)(ws + 48 * MB);
  float*    webuf = (float*)(ws + 56 * MB);                 // 64 KB
  int*      cnt   = (int*)  (ws + 56 * MB + 256 * 1024);    // 32 B
  int*      bidx  = (int*)  (ws + 56 * MB + 320 * 1024);    // 64 KB
  float*    bw    = (float*)(ws + 56 * MB + 448 * 1024);    // 64 KB
  float*    sc    = (float*)(ws + 57 * MB);
  ushort_t* wqkvThi = (ushort_t*)(ws + 57 * MB);            // 6 MB
  ushort_t* wqkvTlo = (ushort_t*)(ws + 63 * MB);            // 6 MB
  ushort_t* woThi = (ushort_t*)(ws + 69 * MB);              // 2 MB
  ushort_t* woTlo = (ushort_t*)(ws + 71 * MB);              // 2 MB
  ushort_t* h1e   = (ushort_t*)(ws + 57 * MB);              // 16 MB
  ushort_t* w1Te  = (ushort_t*)(ws + 73 * MB);              // 8 MB
  ushort_t* w2Te  = (ushort_t*)(ws + 81 * MB);              // 8 MB
  ushort_t* ln2bf = (ushort_t*)(ws + 89 * MB);              // 4 MB

  // ---- attention path: split-bf16 MFMA GEMMs (near-f32 accuracy) ----
  ln_k<2><<<N_TOK, 256, 0, stream>>>(x, ln1w, ln1b, nullptr, ln1hi, ln1lo);
  convT2<<<dim3(D3 / 64, DIM / 64), 256, 0, stream>>>(wqkv, wqkvThi, wqkvTlo, DIM, D3);
  gemm_split<0><<<dim3(D3 / TBN, N_TOK / TBM), 256, 0, stream>>>(
      ln1hi, ln1lo, wqkvThi, wqkvTlo, bqkv, qkv, nullptr, D3, DIM);
  scores_k<<<dim3(8, 8, 64), 256, 0, stream>>>(qkv, sc);
  softmax_k<<<64 * TT, 256, 0, stream>>>(sc);
  ctx_k<<<dim3(8, 64), 256, 0, stream>>>(sc, qkv, ctxhi, ctxlo);
  convT2<<<dim3(DIM / 64, DIM / 64), 256, 0, stream>>>(wo, woThi, woTlo, DIM, DIM);
  gemm_split<1><<<dim3(DIM / TBN, N_TOK / TBM), 256, 0, stream>>>(
      ctxhi, ctxlo, woThi, woTlo, bo, hbuf, x, DIM, DIM);
  ln_k<1><<<N_TOK, 256, 0, stream>>>(hbuf, ln2w, ln2b, ln2f, ln2bf, nullptr);
  gate_k<<<N_TOK / 4, 256, 0, stream>>>(ln2f, wgate, webuf);

  // ---- routed MoE (top-2, bf16 MFMA) ----
  hipMemsetAsync(cnt, 0, 32, stream);
  hipMemsetAsync(accb, 0, (size_t)N_TOK * DIM * 4, stream);
  route_k<<<N_TOK / 256, 256, 0, stream>>>(webuf, cnt, bidx, bw);
  for (int e = 0; e < NEXP; e++){
    // w1[e] f32 [DIM][HID] -> w1Te bf16 [HID][DIM]
    convT<<<dim3(HID / 64, DIM / 64), 256, 0, stream>>>(
        w1 + (size_t)e * DIM * HID, w1Te, DIM, HID);
    moe_gemm<0><<<dim3(HID / TBN, N_TOK / TBM), 256, 0, stream>>>(
        ln2bf, w1Te, b1 + (size_t)e * HID, h1e, nullptr,
        bidx + e * N_TOK, bw + e * N_TOK, cnt + e, HID, DIM);
    // w2[e] f32 [HID][DIM] -> w2Te bf16 [DIM][HID]
    convT<<<dim3(DIM / 64, HID / 64), 256, 0, stream>>>(
        w2 + (size_t)e * HID * DIM, w2Te, HID, DIM);
    moe_gemm<1><<<dim3(DIM / TBN, N_TOK / TBM), 256, 0, stream>>>(
        h1e, w2Te, b2 + (size_t)e * DIM, nullptr, accb,
        bidx + e * N_TOK, bw + e * N_TOK, cnt + e, DIM, HID);
  }
  final_k<<<(N_TOK * DIM) / 256, 256, 0, stream>>>(hbuf, accb, (float*)d_out);
}

// Round 2
// 772.924 us; speedup vs baseline: 2.7046x; 2.3919x over previous
//
#include <hip/hip_runtime.h>
#include <math.h>

typedef unsigned short ushort_t;
using short8 = __attribute__((ext_vector_type(8))) short;
using f32x4  = __attribute__((ext_vector_type(4))) float;

#define N_TOK 2048
#define DIM   1024
#define D3    3072
#define NHEAD 16
#define DH    64
#define TT    512
#define HID   4096
#define NEXP  8

__device__ __forceinline__ float bf2f(ushort_t u){
  union { unsigned int i; float f; } x; x.i = ((unsigned int)u) << 16; return x.f;
}
__device__ __forceinline__ ushort_t f2bf(float f){
  union { unsigned int i; float f; } x; x.f = f;
  unsigned int r = x.i + 0x7fffu + ((x.i >> 16) & 1u);
  return (ushort_t)(r >> 16);
}
__device__ __forceinline__ float gelu_f(float x){
  const float c = 0.7978845608028654f; // sqrt(2/pi)
  float t = tanhf(c * (x + 0.044715f * x * x * x));
  return 0.5f * x * (1.0f + t);
}

// ------- LayerNorm ---------------------------------------------------------
// MODE 1: write f32 out + bf16 outhi            (ln2: gate needs f32, MoE bf16)
// MODE 2: write bf16 hi + bf16 lo only          (ln1: feeds split-bf16 MFMA GEMM)
template<int MODE>
__global__ __launch_bounds__(256) void ln_k(const float* __restrict__ xin,
                                            const float* __restrict__ w,
                                            const float* __restrict__ b,
                                            float* __restrict__ out,
                                            ushort_t* __restrict__ outhi,
                                            ushort_t* __restrict__ outlo){
  int tok = blockIdx.x;
  int t = threadIdx.x;
  float vals[4]; float s = 0.f, ss = 0.f;
#pragma unroll
  for (int i = 0; i < 4; i++){
    int d = t + i * 256;
    float v = xin[(size_t)tok * DIM + d];
    vals[i] = v; s += v; ss += v * v;
  }
  __shared__ float rs[256], rq[256];
  rs[t] = s; rq[t] = ss; __syncthreads();
  for (int k = 128; k > 0; k >>= 1){
    if (t < k){ rs[t] += rs[t + k]; rq[t] += rq[t + k]; }
    __syncthreads();
  }
  float mu  = rs[0] * (1.0f / DIM);
  float var = rq[0] * (1.0f / DIM) - mu * mu;
  float inv = rsqrtf(var + 1e-5f);
#pragma unroll
  for (int i = 0; i < 4; i++){
    int d = t + i * 256;
    float r = (vals[i] - mu) * inv * w[d] + b[d];
    size_t idx = (size_t)tok * DIM + d;
    if (MODE == 1){
      out[idx] = r;
      outhi[idx] = f2bf(r);
    } else {
      ushort_t hv = f2bf(r);
      outhi[idx] = hv;
      outlo[idx] = f2bf(r - bf2f(hv));
    }
  }
}

// -------- Transpose-convert split: src f32 [R][C] -> hi/lo bf16 [C][R] ----
__global__ __launch_bounds__(256) void convT2(const float* __restrict__ src,
                                              ushort_t* __restrict__ dhi,
                                              ushort_t* __restrict__ dlo,
                                              int R, int C){
  __shared__ float tile[64][65];
  int r0 = blockIdx.y * 64, c0 = blockIdx.x * 64;
  int t = threadIdx.x;
  int tc = t & 15, tr = t >> 4;
#pragma unroll
  for (int i = 0; i < 4; i++){
    int r = tr + i * 16;
    float4 v = *(const float4*)&src[(size_t)(r0 + r) * C + c0 + tc * 4];
    tile[r][tc*4 + 0] = v.x; tile[r][tc*4 + 1] = v.y;
    tile[r][tc*4 + 2] = v.z; tile[r][tc*4 + 3] = v.w;
  }
  __syncthreads();
#pragma unroll
  for (int i = 0; i < 4; i++){
    int c = tr + i * 16;                     // output row = source col
    float v0 = tile[tc*4 + 0][c];
    float v1 = tile[tc*4 + 1][c];
    float v2 = tile[tc*4 + 2][c];
    float v3 = tile[tc*4 + 3][c];
    ushort4 oh, ol;
    oh.x = f2bf(v0); ol.x = f2bf(v0 - bf2f(oh.x));
    oh.y = f2bf(v1); ol.y = f2bf(v1 - bf2f(oh.y));
    oh.z = f2bf(v2); ol.z = f2bf(v2 - bf2f(oh.z));
    oh.w = f2bf(v3); ol.w = f2bf(v3 - bf2f(oh.w));
    size_t o = (size_t)(c0 + c) * R + r0 + tc * 4;
    *(ushort4*)&dhi[o] = oh;
    *(ushort4*)&dlo[o] = ol;
  }
}

// -------- Grouped transpose-convert: per-expert f32 [R][C] -> bf16 [C][R] -
__global__ __launch_bounds__(256) void convT_g(const float* __restrict__ src0,
                                               ushort_t* __restrict__ dst0,
                                               int R, int C){
  size_t eo = (size_t)blockIdx.z * R * C;
  const float* src = src0 + eo;
  ushort_t* dst = dst0 + eo;
  __shared__ float tile[64][65];
  int r0 = blockIdx.y * 64, c0 = blockIdx.x * 64;
  int t = threadIdx.x;
  int tc = t & 15, tr = t >> 4;
#pragma unroll
  for (int i = 0; i < 4; i++){
    int r = tr + i * 16;
    float4 v = *(const float4*)&src[(size_t)(r0 + r) * C + c0 + tc * 4];
    tile[r][tc*4 + 0] = v.x; tile[r][tc*4 + 1] = v.y;
    tile[r][tc*4 + 2] = v.z; tile[r][tc*4 + 3] = v.w;
  }
  __syncthreads();
#pragma unroll
  for (int i = 0; i < 4; i++){
    int c = tr + i * 16;                     // output row = source col
    ushort4 o;
    o.x = f2bf(tile[tc*4 + 0][c]);
    o.y = f2bf(tile[tc*4 + 1][c]);
    o.z = f2bf(tile[tc*4 + 2][c]);
    o.w = f2bf(tile[tc*4 + 3][c]);
    *(ushort4*)&dst[(size_t)(c0 + c) * R + r0 + tc * 4] = o;
  }
}

// -------- Split-bf16 MFMA GEMM: C = A*B + bias (+Res), near-f32 accuracy --
#define TBM 128
#define TBN 128
#define TBK 32
#define LDK 40   // padded LDS row stride in bf16 elems

template<int EPI>
__global__ __launch_bounds__(256) void gemm_split(
    const ushort_t* __restrict__ Ahi, const ushort_t* __restrict__ Alo,
    const ushort_t* __restrict__ Bhi, const ushort_t* __restrict__ Blo,
    const float* __restrict__ bias,
    float* __restrict__ C, const float* __restrict__ Res,
    int Nn, int K)
{
  int bm = blockIdx.y * TBM, bn = blockIdx.x * TBN;
  __shared__ ushort_t Ah[TBM * LDK];
  __shared__ ushort_t Al[TBM * LDK];
  __shared__ ushort_t Bh[TBN * LDK];
  __shared__ ushort_t Bl[TBN * LDK];
  int t = threadIdx.x;
  int lane = t & 63, wave = t >> 6;
  int wm = (wave & 1) * 64, wn = (wave >> 1) * 64;

  int r0 = t >> 2, r1 = r0 + 64;
  int kc = (t & 3) * 8;
  const ushort_t* ah0 = Ahi + (size_t)(bm + r0) * K + kc;
  const ushort_t* ah1 = Ahi + (size_t)(bm + r1) * K + kc;
  const ushort_t* al0 = Alo + (size_t)(bm + r0) * K + kc;
  const ushort_t* al1 = Alo + (size_t)(bm + r1) * K + kc;
  const ushort_t* bh0 = Bhi + (size_t)(bn + r0) * K + kc;
  const ushort_t* bh1 = Bhi + (size_t)(bn + r1) * K + kc;
  const ushort_t* bl0 = Blo + (size_t)(bn + r0) * K + kc;
  const ushort_t* bl1 = Blo + (size_t)(bn + r1) * K + kc;

  f32x4 acc[4][4] = {};
  int fm = lane & 15, fk = (lane >> 4) * 8;

  for (int k0 = 0; k0 < K; k0 += TBK){
    uint4 vah0 = *(const uint4*)(ah0 + k0);
    uint4 vah1 = *(const uint4*)(ah1 + k0);
    uint4 val0 = *(const uint4*)(al0 + k0);
    uint4 val1 = *(const uint4*)(al1 + k0);
    uint4 vbh0 = *(const uint4*)(bh0 + k0);
    uint4 vbh1 = *(const uint4*)(bh1 + k0);
    uint4 vbl0 = *(const uint4*)(bl0 + k0);
    uint4 vbl1 = *(const uint4*)(bl1 + k0);
    *(uint4*)&Ah[r0 * LDK + kc] = vah0;
    *(uint4*)&Ah[r1 * LDK + kc] = vah1;
    *(uint4*)&Al[r0 * LDK + kc] = val0;
    *(uint4*)&Al[r1 * LDK + kc] = val1;
    *(uint4*)&Bh[r0 * LDK + kc] = vbh0;
    *(uint4*)&Bh[r1 * LDK + kc] = vbh1;
    *(uint4*)&Bl[r0 * LDK + kc] = vbl0;
    *(uint4*)&Bl[r1 * LDK + kc] = vbl1;
    __syncthreads();
    short8 afh[4], afl[4], bfh[4], bfl[4];
#pragma unroll
    for (int mi = 0; mi < 4; mi++){
      afh[mi] = *(const short8*)&Ah[(wm + mi*16 + fm) * LDK + fk];
      afl[mi] = *(const short8*)&Al[(wm + mi*16 + fm) * LDK + fk];
    }
#pragma unroll
    for (int nj = 0; nj < 4; nj++){
      bfh[nj] = *(const short8*)&Bh[(wn + nj*16 + fm) * LDK + fk];
      bfl[nj] = *(const short8*)&Bl[(wn + nj*16 + fm) * LDK + fk];
    }
#pragma unroll
    for (int mi = 0; mi < 4; mi++)
#pragma unroll
      for (int nj = 0; nj < 4; nj++){
        acc[mi][nj] = __builtin_amdgcn_mfma_f32_16x16x32_bf16(afh[mi], bfh[nj], acc[mi][nj], 0, 0, 0);
        acc[mi][nj] = __builtin_amdgcn_mfma_f32_16x16x32_bf16(afh[mi], bfl[nj], acc[mi][nj], 0, 0, 0);
        acc[mi][nj] = __builtin_amdgcn_mfma_f32_16x16x32_bf16(afl[mi], bfh[nj], acc[mi][nj], 0, 0, 0);
      }
    __syncthreads();
  }

#pragma unroll
  for (int mi = 0; mi < 4; mi++){
    int rowbase = bm + wm + mi*16 + (lane >> 4) * 4;
#pragma unroll
    for (int nj = 0; nj < 4; nj++){
      int n = bn + wn + nj*16 + (lane & 15);
      f32x4 v = acc[mi][nj];
#pragma unroll
      for (int rg = 0; rg < 4; rg++){
        size_t idx = (size_t)(rowbase + rg) * Nn + n;
        float val = v[rg] + bias[n];
        if (EPI == 1) val += Res[idx];
        C[idx] = val;
      }
    }
  }
}

// ---------------- Attention scores: S[bh,q,k] = (Q·K)/8 -------------------
__global__ __launch_bounds__(256) void scores_k(const float* __restrict__ qkv,
                                                float* __restrict__ S){
  int bh = blockIdx.z; int b = bh >> 4, h = bh & 15;
  int q0 = blockIdx.y * 64, k0 = blockIdx.x * 64;
  __shared__ float Qs[64][68];
  __shared__ float Ks[64][68];
  int t = threadIdx.x;
  int r = t >> 2, dp = (t & 3) * 16;
  {
    const float* qp = qkv + (size_t)(b * TT + q0 + r) * D3 + h * DH + dp;
    const float* kp = qkv + (size_t)(b * TT + k0 + r) * D3 + DIM + h * DH + dp;
#pragma unroll
    for (int c = 0; c < 4; c++){
      float4 qv = *(const float4*)(qp + c * 4);
      float4 kv = *(const float4*)(kp + c * 4);
      Qs[dp + c*4 + 0][r] = qv.x; Qs[dp + c*4 + 1][r] = qv.y;
      Qs[dp + c*4 + 2][r] = qv.z; Qs[dp + c*4 + 3][r] = qv.w;
      Ks[dp + c*4 + 0][r] = kv.x; Ks[dp + c*4 + 1][r] = kv.y;
      Ks[dp + c*4 + 2][r] = kv.z; Ks[dp + c*4 + 3][r] = kv.w;
    }
  }
  __syncthreads();
  int tx = t & 15, ty = t >> 4;
  float acc[4][4] = {};
#pragma unroll 8
  for (int d = 0; d < 64; d++){
    float4 qv = *(const float4*)&Qs[d][ty * 4];
    float4 kv = *(const float4*)&Ks[d][tx * 4];
    float qa[4] = {qv.x,qv.y,qv.z,qv.w};
    float ka[4] = {kv.x,kv.y,kv.z,kv.w};
#pragma unroll
    for (int i = 0; i < 4; i++)
#pragma unroll
      for (int j = 0; j < 4; j++)
        acc[i][j] += qa[i] * ka[j];
  }
#pragma unroll
  for (int i = 0; i < 4; i++)
#pragma unroll
    for (int j = 0; j < 4; j++)
      S[((size_t)bh * TT + q0 + ty*4 + i) * TT + k0 + tx*4 + j] = acc[i][j] * 0.125f;
}

// ---------------- Softmax over rows of 512 --------------------------------
__global__ __launch_bounds__(256) void softmax_k(float* __restrict__ S){
  size_t row = blockIdx.x;
  float* p = S + row * TT;
  int t = threadIdx.x;
  float v0 = p[t], v1 = p[t + 256];
  __shared__ float red[256];
  red[t] = fmaxf(v0, v1); __syncthreads();
  for (int k = 128; k > 0; k >>= 1){ if (t < k) red[t] = fmaxf(red[t], red[t + k]); __syncthreads(); }
  float m = red[0]; __syncthreads();
  float e0 = expf(v0 - m), e1 = expf(v1 - m);
  red[t] = e0 + e1; __syncthreads();
  for (int k = 128; k > 0; k >>= 1){ if (t < k) red[t] += red[t + k]; __syncthreads(); }
  float inv = 1.0f / red[0];
  p[t] = e0 * inv; p[t + 256] = e1 * inv;
}

// ------- ctx = P @ V; write bf16 hi/lo [2048][1024] for split MFMA --------
__global__ __launch_bounds__(256) void ctx_k(const float* __restrict__ P,
                                             const float* __restrict__ qkv,
                                             ushort_t* __restrict__ chi,
                                             ushort_t* __restrict__ clo){
  int bh = blockIdx.y; int b = bh >> 4, h = bh & 15;
  int q0 = blockIdx.x * 64;
  __shared__ float Ps[16][68];
  __shared__ float Vs[16][68];
  int t = threadIdx.x;
  int tx = t & 15, ty = t >> 4;
  int pq = t >> 2, pk = (t & 3) * 4;
  int vk = t >> 4, vd = (t & 15) * 4;
  float acc[4][4] = {};
  for (int kk = 0; kk < TT; kk += 16){
    float4 pv = *(const float4*)&P[((size_t)bh * TT + q0 + pq) * TT + kk + pk];
    Ps[pk + 0][pq] = pv.x; Ps[pk + 1][pq] = pv.y;
    Ps[pk + 2][pq] = pv.z; Ps[pk + 3][pq] = pv.w;
    float4 vv = *(const float4*)&qkv[(size_t)(b * TT + kk + vk) * D3 + 2 * DIM + h * DH + vd];
    Vs[vk][vd + 0] = vv.x; Vs[vk][vd + 1] = vv.y;
    Vs[vk][vd + 2] = vv.z; Vs[vk][vd + 3] = vv.w;
    __syncthreads();
#pragma unroll
    for (int k = 0; k < 16; k++){
      float4 a = *(const float4*)&Ps[k][ty * 4];
      float4 bb = *(const float4*)&Vs[k][tx * 4];
      float aa[4] = {a.x,a.y,a.z,a.w};
      float bv[4] = {bb.x,bb.y,bb.z,bb.w};
#pragma unroll
      for (int i = 0; i < 4; i++)
#pragma unroll
        for (int j = 0; j < 4; j++)
          acc[i][j] += aa[i] * bv[j];
    }
    __syncthreads();
  }
#pragma unroll
  for (int i = 0; i < 4; i++)
#pragma unroll
    for (int j = 0; j < 4; j++){
      float v = acc[i][j];
      size_t idx = (size_t)(b * TT + q0 + ty*4 + i) * DIM + h * DH + tx*4 + j;
      ushort_t hv = f2bf(v);
      chi[idx] = hv;
      clo[idx] = f2bf(v - bf2f(hv));
    }
}

// -------- Gate (exact f32) + top-2 renorm weights -------------------------
__global__ __launch_bounds__(256) void gate_k(const float* __restrict__ ln2f,
                                              const float* __restrict__ wg,
                                              float* __restrict__ we){
  int tok = blockIdx.x * 4 + (threadIdx.x >> 6);
  int lane = threadIdx.x & 63;
  float acc[8] = {};
  for (int d = lane; d < DIM; d += 64){
    float x = ln2f[(size_t)tok * DIM + d];
    float4 w0 = *(const float4*)&wg[d * 8];
    float4 w1v = *(const float4*)&wg[d * 8 + 4];
    float wv[8] = {w0.x,w0.y,w0.z,w0.w,w1v.x,w1v.y,w1v.z,w1v.w};
#pragma unroll
    for (int e = 0; e < 8; e++) acc[e] += x * wv[e];
  }
#pragma unroll
  for (int off = 32; off > 0; off >>= 1){
#pragma unroll
    for (int e = 0; e < 8; e++) acc[e] += __shfl_down(acc[e], off);
  }
  if (lane == 0){
    float m = acc[0];
    for (int e = 1; e < 8; e++) m = fmaxf(m, acc[e]);
    float pr[8], s = 0.f;
    for (int e = 0; e < 8; e++){ pr[e] = expf(acc[e] - m); s += pr[e]; }
    for (int e = 0; e < 8; e++) pr[e] /= s;
    int i0 = 0;
    for (int e = 1; e < 8; e++) if (pr[e] > pr[i0]) i0 = e;
    int i1 = (i0 == 0) ? 1 : 0;
    for (int e = 0; e < 8; e++) if (e != i0 && pr[e] > pr[i1]) i1 = e;
    float sm = pr[i0] + pr[i1];
    for (int e = 0; e < 8; e++)
      we[(size_t)tok * 8 + e] = (e == i0) ? pr[i0] / sm : ((e == i1) ? pr[i1] / sm : 0.f);
  }
}

// -------- Routing: bucket tokens per expert (device-side counts) ----------
__global__ __launch_bounds__(256) void route_k(const float* __restrict__ we,
                                               int* __restrict__ cnt,
                                               int* __restrict__ gidx,
                                               float* __restrict__ gw){
  int tok = blockIdx.x * 256 + threadIdx.x;
#pragma unroll
  for (int e = 0; e < NEXP; e++){
    float w = we[(size_t)tok * NEXP + e];
    if (w > 0.f){
      int p = atomicAdd(&cnt[e], 1);
      gidx[e * N_TOK + p] = tok;
      gw[e * N_TOK + p] = w;
    }
  }
}

// -------- Exclusive scan of 8 expert counts -------------------------------
__global__ void scan_k(const int* __restrict__ cnt, int* __restrict__ off){
  if (threadIdx.x == 0){
    int s = 0;
    for (int e = 0; e < NEXP; e++){ off[e] = s; s += cnt[e]; }
  }
}

// -------- Grouped MFMA bf16 expert GEMM (all experts, one launch) ---------
// blockIdx.y encodes (expert e = y>>4, row-block lb = y&15).
// EPI 0: A rows gathered via gidx[e][...]; out h1 row = off[e]+r (gelu+bf16)
// EPI 1: A rows dense from h1 at off[e]+r; scatter atomicAdd into Of[tok][n]
template<int EPI>
__global__ __launch_bounds__(256) void moe_gemm_g(
    const ushort_t* __restrict__ A,      // EPI0: ln2bf [N_TOK][K]; EPI1: h1e [4096][K]
    const ushort_t* __restrict__ BT_all, // bf16 [E][N][K]
    const float* __restrict__ bias_all,  // [E][N]
    ushort_t* __restrict__ Obf,          // EPI0 out: h1e [4096][Nn]
    float* __restrict__ Of,              // EPI1 out: accb [N_TOK][Nn]
    const int* __restrict__ gidx_all,    // [E][N_TOK]
    const float* __restrict__ gw_all,    // [E][N_TOK]
    const int* __restrict__ cnt,         // [E]
    const int* __restrict__ off,         // [E] exclusive scan
    int Nn, int K)
{
  int e  = blockIdx.y >> 4;
  int c  = cnt[e];
  int bm = (blockIdx.y & 15) * TBM;
  if (bm >= c) return;
  int bn = blockIdx.x * TBN;
  const int* gidx = gidx_all + e * N_TOK;
  const float* gwp = gw_all + e * N_TOK;
  const ushort_t* BT = BT_all + (size_t)e * Nn * K;
  const float* bias = bias_all + (size_t)e * Nn;
  int obase = off[e];

  __shared__ ushort_t As[TBM * LDK];
  __shared__ ushort_t Bs[TBN * LDK];
  int t = threadIdx.x;
  int lane = t & 63, wave = t >> 6;
  int wm = (wave & 1) * 64, wn = (wave >> 1) * 64;

  int r0 = t >> 2, r1 = r0 + 64;
  int kc = (t & 3) * 8;
  size_t ga0, ga1;
  if (EPI == 0){
    int g0 = bm + r0, g1 = bm + r1;
    ga0 = (size_t)((g0 < c) ? gidx[g0] : gidx[bm]);
    ga1 = (size_t)((g1 < c) ? gidx[g1] : gidx[bm]);
  } else {
    int mx = 2 * N_TOK - 1;
    int g0 = obase + bm + r0; if (g0 > mx) g0 = mx;
    int g1 = obase + bm + r1; if (g1 > mx) g1 = mx;
    ga0 = (size_t)g0; ga1 = (size_t)g1;
  }
  const ushort_t* a0p = A + ga0 * K + kc;
  const ushort_t* a1p = A + ga1 * K + kc;
  const ushort_t* b0p = BT + (size_t)(bn + r0) * K + kc;
  const ushort_t* b1p = BT + (size_t)(bn + r1) * K + kc;

  f32x4 acc[4][4] = {};
  int fm = lane & 15, fk = (lane >> 4) * 8;

  // register prefetch of tile 0
  uint4 av0 = *(const uint4*)(a0p);
  uint4 av1 = *(const uint4*)(a1p);
  uint4 bv0 = *(const uint4*)(b0p);
  uint4 bv1 = *(const uint4*)(b1p);

  for (int k0 = 0; k0 < K; k0 += TBK){
    *(uint4*)&As[r0 * LDK + kc] = av0;
    *(uint4*)&As[r1 * LDK + kc] = av1;
    *(uint4*)&Bs[r0 * LDK + kc] = bv0;
    *(uint4*)&Bs[r1 * LDK + kc] = bv1;
    __syncthreads();
    int kn = k0 + TBK;
    if (kn < K){               // issue next-tile loads; in flight during MFMA
      av0 = *(const uint4*)(a0p + kn);
      av1 = *(const uint4*)(a1p + kn);
      bv0 = *(const uint4*)(b0p + kn);
      bv1 = *(const uint4*)(b1p + kn);
    }
    short8 af[4], bfr[4];
#pragma unroll
    for (int mi = 0; mi < 4; mi++)
      af[mi] = *(const short8*)&As[(wm + mi*16 + fm) * LDK + fk];
#pragma unroll
    for (int nj = 0; nj < 4; nj++)
      bfr[nj] = *(const short8*)&Bs[(wn + nj*16 + fm) * LDK + fk];
#pragma unroll
    for (int mi = 0; mi < 4; mi++)
#pragma unroll
      for (int nj = 0; nj < 4; nj++)
        acc[mi][nj] = __builtin_amdgcn_mfma_f32_16x16x32_bf16(af[mi], bfr[nj], acc[mi][nj], 0, 0, 0);
    __syncthreads();
  }

  // epilogue: C/D layout col=lane&15, row=(lane>>4)*4+reg  [m89-verified]
#pragma unroll
  for (int mi = 0; mi < 4; mi++){
    int rowbase = bm + wm + mi*16 + (lane >> 4) * 4;
#pragma unroll
    for (int nj = 0; nj < 4; nj++){
      int n = bn + wn + nj*16 + (lane & 15);
      f32x4 v = acc[mi][nj];
#pragma unroll
      for (int rg = 0; rg < 4; rg++){
        int r = rowbase + rg;
        if (r < c){
          float val = v[rg] + bias[n];
          if (EPI == 0){
            Obf[(size_t)(obase + r) * Nn + n] = f2bf(gelu_f(val));
          } else {
            int tok = gidx[r];
            atomicAdd(&Of[(size_t)tok * Nn + n], gwp[r] * val);
          }
        }
      }
    }
  }
}

// ---------------- Final: out = h + moe_acc (f32) --------------------------
__global__ __launch_bounds__(256) void final_k(const float* __restrict__ h,
                                               const float* __restrict__ acc,
                                               float* __restrict__ out){
  size_t i = (size_t)blockIdx.x * 256 + threadIdx.x;
  out[i] = h[i] + acc[i];
}

extern "C" void kernel_launch(void* const* d_in, const int* in_sizes, int n_in,
                              void* d_out, int out_size, void* d_ws, size_t ws_size,
                              hipStream_t stream){
  const float* x     = (const float*)d_in[0];
  const float* ln1w  = (const float*)d_in[1];
  const float* ln1b  = (const float*)d_in[2];
  const float* ln2w  = (const float*)d_in[3];
  const float* ln2b  = (const float*)d_in[4];
  const float* wqkv  = (const float*)d_in[5];
  const float* bqkv  = (const float*)d_in[6];
  const float* wo    = (const float*)d_in[7];
  const float* bo    = (const float*)d_in[8];
  const float* wgate = (const float*)d_in[9];
  const float* w1    = (const float*)d_in[10];
  const float* b1    = (const float*)d_in[11];
  const float* w2    = (const float*)d_in[12];
  const float* b2    = (const float*)d_in[13];

  // Workspace map (121 MB peak, all lifetimes verified disjoint):
  //  [0,8)    hbuf f32 (out-proj..end)     | attn: ln1hi[0,4) ln1lo[4,8) (dead after QKV)
  //  [8,16)   accb f32 (memset..end)       | attn: wqkvThi[8,14) wqkvTlo[14,20) (dead after QKV)
  //  [16,20)  ln2bf bf16 (ln2..GEMM1)
  //  [20,52)  h1e bf16 [4096][HID] (GEMM1..GEMM2) | attn: qkv[20,44) (dead after ctx),
  //           ctxhi[44,48) ctxlo[48,52) (dead after out-proj); ln2f f32 [24,32) (ln2..gate)
  //  [52,56)  woThi[52,54) woTlo[54,56) (dead after out-proj)
  //  [56,120) sc f32 (dead after ctx) -> wTe bf16 [E][N][K] (convW1..GEMM1, convW2..GEMM2)
  //  [120,121) webuf 64K | cnt 32B @+256K | off 32B @+260K | bidx 64K @+320K | bw 64K @+448K
  char* ws = (char*)d_ws;
  const size_t MB = 1024 * 1024;
  float*    hbuf  = (float*)(ws + 0 * MB);
  ushort_t* ln1hi = (ushort_t*)(ws + 0 * MB);
  ushort_t* ln1lo = (ushort_t*)(ws + 4 * MB);
  float*    accb  = (float*)(ws + 8 * MB);
  ushort_t* wqkvThi = (ushort_t*)(ws + 8 * MB);             // 6 MB
  ushort_t* wqkvTlo = (ushort_t*)(ws + 14 * MB);            // 6 MB
  ushort_t* ln2bf = (ushort_t*)(ws + 16 * MB);              // 4 MB
  ushort_t* h1e   = (ushort_t*)(ws + 20 * MB);              // 32 MB
  float*    qkv   = (float*)(ws + 20 * MB);                 // 24 MB
  float*    ln2f  = (float*)(ws + 24 * MB);                 // 8 MB
  ushort_t* ctxhi = (ushort_t*)(ws + 44 * MB);
  ushort_t* ctxlo = (ushort_t*)(ws + 48 * MB);
  ushort_t* woThi = (ushort_t*)(ws + 52 * MB);              // 2 MB
  ushort_t* woTlo = (ushort_t*)(ws + 54 * MB);              // 2 MB
  float*    sc    = (float*)(ws + 56 * MB);                 // 64 MB
  ushort_t* wTe   = (ushort_t*)(ws + 56 * MB);              // 64 MB
  float*    webuf = (float*)(ws + 120 * MB);                // 64 KB
  int*      cnt   = (int*)  (ws + 120 * MB + 256 * 1024);   // 32 B
  int*      off   = (int*)  (ws + 120 * MB + 260 * 1024);   // 32 B
  int*      bidx  = (int*)  (ws + 120 * MB + 320 * 1024);   // 64 KB
  float*    bw    = (float*)(ws + 120 * MB + 448 * 1024);   // 64 KB

  // ---- attention path: split-bf16 MFMA GEMMs (near-f32 accuracy) ----
  ln_k<2><<<N_TOK, 256, 0, stream>>>(x, ln1w, ln1b, nullptr, ln1hi, ln1lo);
  convT2<<<dim3(D3 / 64, DIM / 64), 256, 0, stream>>>(wqkv, wqkvThi, wqkvTlo, DIM, D3);
  gemm_split<0><<<dim3(D3 / TBN, N_TOK / TBM), 256, 0, stream>>>(
      ln1hi, ln1lo, wqkvThi, wqkvTlo, bqkv, qkv, nullptr, D3, DIM);
  scores_k<<<dim3(8, 8, 64), 256, 0, stream>>>(qkv, sc);
  softmax_k<<<64 * TT, 256, 0, stream>>>(sc);
  ctx_k<<<dim3(8, 64), 256, 0, stream>>>(sc, qkv, ctxhi, ctxlo);
  // sc dead -> convert ALL expert w1 into wTe (one launch)
  convT_g<<<dim3(HID / 64, DIM / 64, NEXP), 256, 0, stream>>>(w1, wTe, DIM, HID);
  convT2<<<dim3(DIM / 64, DIM / 64), 256, 0, stream>>>(wo, woThi, woTlo, DIM, DIM);
  gemm_split<1><<<dim3(DIM / TBN, N_TOK / TBM), 256, 0, stream>>>(
      ctxhi, ctxlo, woThi, woTlo, bo, hbuf, x, DIM, DIM);
  ln_k<1><<<N_TOK, 256, 0, stream>>>(hbuf, ln2w, ln2b, ln2f, ln2bf, nullptr);
  gate_k<<<N_TOK / 4, 256, 0, stream>>>(ln2f, wgate, webuf);

  // ---- routed MoE: grouped launches, all experts concurrent ----
  hipMemsetAsync(cnt, 0, 32, stream);
  hipMemsetAsync(accb, 0, (size_t)N_TOK * DIM * 4, stream);
  route_k<<<N_TOK / 256, 256, 0, stream>>>(webuf, cnt, bidx, bw);
  scan_k<<<1, 64, 0, stream>>>(cnt, off);
  moe_gemm_g<0><<<dim3(HID / TBN, NEXP * 16), 256, 0, stream>>>(
      ln2bf, wTe, b1, h1e, nullptr, bidx, bw, cnt, off, HID, DIM);
  convT_g<<<dim3(DIM / 64, HID / 64, NEXP), 256, 0, stream>>>(w2, wTe, HID, DIM);
  moe_gemm_g<1><<<dim3(DIM / TBN, NEXP * 16), 256, 0, stream>>>(
      h1e, wTe, b2, nullptr, accb, bidx, bw, cnt, off, DIM, HID);
  final_k<<<(N_TOK * DIM) / 256, 256, 0, stream>>>(hbuf, accb, (float*)d_out);
}